// Round 11
// baseline (10874.538 us; speedup 1.0000x reference)
//
#include <hip/hip_runtime.h>

#define N_DIM 100000
#define M_DIM 200000
#define NNZ_A 2000000
#define NNZ_P 500000
#define NMSUM 300000
#define NM1   300001
#define CG_ITERS 20
#define TPB 256
#define NSLOT 512

// slots: sc[0]=xTPx, sc[1..3]=dd_t dots, sc[8..9]=rhs-FTmv dots,
// per-iter base 16+8*it: {d1,d2,e1,e2,pq}, gam[] at sc+432 (0..50)

__device__ __forceinline__ void blk_red_add(double v, double* dst) {
    __shared__ double sb[TPB];
    int tid = threadIdx.x;
    sb[tid] = v;
    __syncthreads();
    for (int sh = TPB / 2; sh > 0; sh >>= 1) {
        if (tid < sh) sb[tid] += sb[tid + sh];
        __syncthreads();
    }
    if (tid == 0) atomicAdd(dst, sb[0]);
}

// ---------- init ----------
__global__ __launch_bounds__(TPB) void k_init(double* sc, const float* y, const float* s,
                                              double* mask_d, double* pim_d, double* Px,
                                              double* dpx, double* dd, double* r,
                                              double* xcg, double* tm) {
    int i = blockIdx.x * TPB + threadIdx.x;
    if (i < NSLOT) sc[i] = 0.0;
    if (i < M_DIM) {
        double v = (double)y[i] - (double)s[i];
        mask_d[i] = v > 0.0 ? 1.0 : 0.0;
        pim_d[i]  = v > 0.0 ? v : 0.0;
        tm[i] = 0.0;
    }
    if (i < N_DIM) { Px[i] = 0.0; dpx[i] = 0.0; }
    if (i < NM1) { dd[i] = 0.0; r[i] = 0.0; xcg[i] = 0.0; }
}

// ---------- generic COO scatter: vout[rows[k]] += sgn*vals[k]*vin[cols[k]] ----------
__global__ __launch_bounds__(TPB) void k_sp(const float* vals, const int* rows, const int* cols,
                                            const double* vin, double* vout, double sgn, long nnz) {
    long k = (long)blockIdx.x * TPB + threadIdx.x;
    if (k < nnz) atomicAdd(&vout[rows[k]], sgn * (double)vals[k] * vin[cols[k]]);
}
__global__ __launch_bounds__(TPB) void k_spf(const float* vals, const int* rows, const int* cols,
                                             const float* vin, double* vout, double sgn, long nnz) {
    long k = (long)blockIdx.x * TPB + threadIdx.x;
    if (k < nnz) atomicAdd(&vout[rows[k]], sgn * (double)vals[k] * (double)vin[cols[k]]);
}

// ---------- dots ----------
__global__ __launch_bounds__(TPB) void k_dot_dd(const double* a, const double* b, long len, double* dst) {
    long i = (long)blockIdx.x * TPB + threadIdx.x;
    double loc = 0.0;
    if (i < len) loc = a[i] * b[i];
    blk_red_add(loc, dst);
}
__global__ __launch_bounds__(TPB) void k_dot_fd(const float* a, const double* b, long len, double* dst) {
    long i = (long)blockIdx.x * TPB + threadIdx.x;
    double loc = 0.0;
    if (i < len) loc = (double)a[i] * b[i];
    blk_red_add(loc, dst);
}
__global__ __launch_bounds__(TPB) void k_dot_ff(const float* a, const float* b, long len, double* dst) {
    long i = (long)blockIdx.x * TPB + threadIdx.x;
    double loc = 0.0;
    if (i < len) loc = (double)a[i] * (double)b[i];
    blk_red_add(loc, dst);
}

// ---------- setup pieces ----------
__global__ __launch_bounds__(TPB) void k_c3e(const float* q, const double* Px, double* c3) {
    int i = blockIdx.x * TPB + threadIdx.x;
    if (i < N_DIM) c3[i] = (double)q[i] + 2.0 * Px[i];
}
__global__ __launch_bounds__(TPB) void k_dd_n(const double* dpx, const float* dq, double* dd) {
    int i = blockIdx.x * TPB + threadIdx.x;
    if (i < N_DIM) dd[i] = dpx[i] + (double)dq[i];   // dPmv(x) + dq*tau ; dATmv added after
}
__global__ __launch_bounds__(TPB) void k_dd_m(const float* db, double* dd) {
    int j = blockIdx.x * TPB + threadIdx.x;
    if (j < M_DIM) dd[N_DIM + j] += (double)db[j];   // on top of -dAmv(x)
}
__global__ __launch_bounds__(64) void k_dd_t(double* sc, double* dd) {
    if (threadIdx.x == 0) dd[NMSUM] = -sc[1] - sc[2] - sc[3];
}
__global__ __launch_bounds__(TPB) void k_neg(double* dd) {
    int i = blockIdx.x * TPB + threadIdx.x;
    if (i < NM1) dd[i] = -dd[i];
}

// ---------- Fmv pieces ----------
__global__ __launch_bounds__(TPB) void k_um(const double* mask_d, const double* V, double* um) {
    int j = blockIdx.x * TPB + threadIdx.x;
    if (j < M_DIM) um[j] = mask_d[j] * V[N_DIM + j];
}
__global__ __launch_bounds__(TPB) void k_f_n(const float* q, const double* V, double* O) {
    int i = blockIdx.x * TPB + threadIdx.x;
    if (i < N_DIM) {
        double ut = V[NMSUM];
        double r1 = O[i] + (double)q[i] * ut;
        O[i] = (r1 - V[i]) + V[i];
    }
}
__global__ __launch_bounds__(TPB) void k_f_m(const float* b, const double* um, const double* V, double* O) {
    int j = blockIdx.x * TPB + threadIdx.x;
    if (j < M_DIM) {
        double ut = V[NMSUM];
        double r2 = O[N_DIM + j] + (double)b[j] * ut;
        O[N_DIM + j] = (r2 - um[j]) + V[N_DIM + j];
    }
}
__global__ __launch_bounds__(64) void k_f_t(const double* d1, const double* d2, const double* xtpx,
                                            const double* V, double* O) {
    if (threadIdx.x == 0) {
        double ut = V[NMSUM];
        double r3 = -(*d1) - (*d2) + (*xtpx) * ut;
        O[NMSUM] = (r3 - ut) + ut;
    }
}

// ---------- FTmv pieces ----------
__global__ __launch_bounds__(TPB) void k_ft_n(const double* c3, const double* W, double* U) {
    int i = blockIdx.x * TPB + threadIdx.x;
    if (i < N_DIM) U[i] = U[i] - c3[i] * W[NMSUM];
}
__global__ __launch_bounds__(TPB) void k_ft_m(const double* mask_d, const float* b,
                                              const double* tm, const double* W, double* U) {
    int j = blockIdx.x * TPB + threadIdx.x;
    if (j < M_DIM) {
        double wt = W[NMSUM];
        double tmv = tm[j] - (double)b[j] * wt;
        double wm = W[N_DIM + j];
        U[N_DIM + j] = mask_d[j] * (tmv - wm) + wm;
    }
}
__global__ __launch_bounds__(64) void k_ft_t(const double* e1, const double* e2, const double* xtpx,
                                             const double* W, double* U) {
    if (threadIdx.x == 0) U[NMSUM] = (*e1) + (*e2) + (*xtpx) * W[NMSUM];
}

// ---------- CG ----------
__global__ __launch_bounds__(TPB) void k_cginit(const double* r, double* p, double* gam0) {
    int i = blockIdx.x * TPB + threadIdx.x;
    double loc = 0.0;
    if (i < NM1) { double v = r[i]; p[i] = v; loc = v * v; }
    blk_red_add(loc, gam0);
}
__global__ __launch_bounds__(TPB) void k_zero_iter(double* Fp, double* Ap, double* tm) {
    int i = blockIdx.x * TPB + threadIdx.x;
    if (i < NM1) Fp[i] = 0.0;
    if (i < N_DIM) Ap[i] = 0.0;
    if (i < M_DIM) tm[i] = 0.0;
}
__global__ __launch_bounds__(TPB) void k_xr(const double* p, const double* Ap,
                                            const double* gold, const double* pq,
                                            double* xcg, double* r, double* gnew) {
    int i = blockIdx.x * TPB + threadIdx.x;
    double alpha = *gold / *pq;
    double loc = 0.0;
    if (i < NM1) {
        xcg[i] += alpha * p[i];
        double rn = r[i] - alpha * Ap[i];
        r[i] = rn;
        loc = rn * rn;
    }
    blk_red_add(loc, gnew);
}
__global__ __launch_bounds__(TPB) void k_up(const double* r, const double* gnew,
                                            const double* gold, double* p) {
    int i = blockIdx.x * TPB + threadIdx.x;
    if (i < NM1) {
        double beta = *gnew / *gold;
        p[i] = r[i] + beta * p[i];
    }
}

__global__ __launch_bounds__(TPB) void k_final(const double* xcg, const double* mask_d,
                                               const float* x, const float* y, const float* s,
                                               float* out) {
    int i = blockIdx.x * TPB + threadIdx.x;
    double dzt = xcg[NMSUM];
    if (i < N_DIM) {
        out[i] = (float)(xcg[i] - (double)x[i] * dzt);
    } else if (i < NMSUM) {
        int j = i - N_DIM;
        double dzm = xcg[N_DIM + j];
        double t = mask_d[j] * dzm;
        out[N_DIM + j] = (float)(t - (double)y[j] * dzt);
        out[N_DIM + M_DIM + j] = (float)(t - dzm - (double)s[j] * dzt);
    }
}

extern "C" void kernel_launch(void* const* d_in, const int* in_sizes, int n_in,
                              void* d_out, int out_size, void* d_ws, size_t ws_size,
                              hipStream_t stream) {
    const int*   Pr  = (const int*)d_in[0];
    const int*   Pc  = (const int*)d_in[1];
    const float* Pv  = (const float*)d_in[2];
    const int*   Ar  = (const int*)d_in[3];
    const int*   Ac  = (const int*)d_in[4];
    const float* Av  = (const float*)d_in[5];
    const float* q   = (const float*)d_in[6];
    const float* b   = (const float*)d_in[7];
    const float* x   = (const float*)d_in[8];
    const float* yv  = (const float*)d_in[9];
    const float* sv  = (const float*)d_in[10];
    const float* dPv = (const float*)d_in[11];
    const float* dAv = (const float*)d_in[12];
    const float* dq  = (const float*)d_in[13];
    const float* db  = (const float*)d_in[14];
    float* out = (float*)d_out;

    char* wp = (char*)d_ws;
    double* sc     = (double*)wp; wp += NSLOT * 8;
    double* mask_d = (double*)wp; wp += M_DIM * 8;
    double* pim_d  = (double*)wp; wp += M_DIM * 8;
    double* Px     = (double*)wp; wp += N_DIM * 8;
    double* dpx    = (double*)wp; wp += N_DIM * 8;
    double* c3     = (double*)wp; wp += N_DIM * 8;
    double* um     = (double*)wp; wp += M_DIM * 8;
    double* tm     = (double*)wp; wp += M_DIM * 8;
    double* dd     = (double*)wp; wp += NM1 * 8;
    double* r      = (double*)wp; wp += NM1 * 8;
    double* p      = (double*)wp; wp += NM1 * 8;
    double* xcg    = (double*)wp; wp += NM1 * 8;
    double* Fp     = (double*)wp; wp += NM1 * 8;
    double* Ap     = (double*)wp; wp += NM1 * 8;

    double* xtpx = sc + 0;
    double* gam  = sc + 432;

    auto g = [](long n) { return dim3((unsigned)((n + TPB - 1) / TPB)); };

    hipLaunchKernelGGL(k_init, g(NM1), dim3(TPB), 0, stream, sc, yv, sv, mask_d, pim_d, Px, dpx, dd, r, xcg, tm);
    hipLaunchKernelGGL(k_spf, g(NNZ_P), dim3(TPB), 0, stream, Pv, Pr, Pc, x, Px, 1.0, (long)NNZ_P);
    hipLaunchKernelGGL(k_dot_fd, g(N_DIM), dim3(TPB), 0, stream, x, Px, (long)N_DIM, xtpx);
    hipLaunchKernelGGL(k_c3e, g(N_DIM), dim3(TPB), 0, stream, q, Px, c3);
    hipLaunchKernelGGL(k_spf, g(NNZ_P), dim3(TPB), 0, stream, dPv, Pr, Pc, x, dpx, 1.0, (long)NNZ_P);
    hipLaunchKernelGGL(k_dd_n, g(N_DIM), dim3(TPB), 0, stream, dpx, dq, dd);
    hipLaunchKernelGGL(k_sp, g(NNZ_A), dim3(TPB), 0, stream, dAv, Ac, Ar, pim_d, dd, 1.0, (long)NNZ_A);
    hipLaunchKernelGGL(k_spf, g(NNZ_A), dim3(TPB), 0, stream, dAv, Ar, Ac, x, dd + N_DIM, -1.0, (long)NNZ_A);
    hipLaunchKernelGGL(k_dd_m, g(M_DIM), dim3(TPB), 0, stream, db, dd);
    hipLaunchKernelGGL(k_dot_ff, g(N_DIM), dim3(TPB), 0, stream, dq, x, (long)N_DIM, sc + 1);
    hipLaunchKernelGGL(k_dot_fd, g(M_DIM), dim3(TPB), 0, stream, db, pim_d, (long)M_DIM, sc + 2);
    hipLaunchKernelGGL(k_dot_fd, g(N_DIM), dim3(TPB), 0, stream, x, dpx, (long)N_DIM, sc + 3);
    hipLaunchKernelGGL(k_dd_t, dim3(1), dim3(64), 0, stream, sc, dd);
    hipLaunchKernelGGL(k_neg, g(NM1), dim3(TPB), 0, stream, dd);
    hipLaunchKernelGGL(k_sp, g(NNZ_P), dim3(TPB), 0, stream, Pv, Pr, Pc, dd, r, 1.0, (long)NNZ_P);
    hipLaunchKernelGGL(k_sp, g(NNZ_A), dim3(TPB), 0, stream, Av, Ac, Ar, dd + N_DIM, r, -1.0, (long)NNZ_A);
    hipLaunchKernelGGL(k_ft_n, g(N_DIM), dim3(TPB), 0, stream, c3, dd, r);
    hipLaunchKernelGGL(k_sp, g(NNZ_A), dim3(TPB), 0, stream, Av, Ar, Ac, dd, tm, 1.0, (long)NNZ_A);
    hipLaunchKernelGGL(k_ft_m, g(M_DIM), dim3(TPB), 0, stream, mask_d, b, tm, dd, r);
    hipLaunchKernelGGL(k_dot_fd, g(N_DIM), dim3(TPB), 0, stream, q, dd, (long)N_DIM, sc + 8);
    hipLaunchKernelGGL(k_dot_fd, g(M_DIM), dim3(TPB), 0, stream, b, dd + N_DIM, (long)M_DIM, sc + 9);
    hipLaunchKernelGGL(k_ft_t, dim3(1), dim3(64), 0, stream, sc + 8, sc + 9, xtpx, dd, r);
    hipLaunchKernelGGL(k_cginit, g(NM1), dim3(TPB), 0, stream, r, p, gam);

    for (int it = 0; it < CG_ITERS; ++it) {
        double* d1 = sc + 16 + 8 * it;
        double* d2 = d1 + 1;
        double* e1 = d1 + 2;
        double* e2 = d1 + 3;
        double* pq = d1 + 4;
        hipLaunchKernelGGL(k_zero_iter, g(NM1), dim3(TPB), 0, stream, Fp, Ap, tm);
        hipLaunchKernelGGL(k_um, g(M_DIM), dim3(TPB), 0, stream, mask_d, p, um);
        hipLaunchKernelGGL(k_sp, g(NNZ_P), dim3(TPB), 0, stream, Pv, Pr, Pc, p, Fp, 1.0, (long)NNZ_P);
        hipLaunchKernelGGL(k_sp, g(NNZ_A), dim3(TPB), 0, stream, Av, Ac, Ar, um, Fp, 1.0, (long)NNZ_A);
        hipLaunchKernelGGL(k_f_n, g(N_DIM), dim3(TPB), 0, stream, q, p, Fp);
        hipLaunchKernelGGL(k_sp, g(NNZ_A), dim3(TPB), 0, stream, Av, Ar, Ac, p, Fp + N_DIM, -1.0, (long)NNZ_A);
        hipLaunchKernelGGL(k_f_m, g(M_DIM), dim3(TPB), 0, stream, b, um, p, Fp);
        hipLaunchKernelGGL(k_dot_dd, g(N_DIM), dim3(TPB), 0, stream, c3, p, (long)N_DIM, d1);
        hipLaunchKernelGGL(k_dot_fd, g(M_DIM), dim3(TPB), 0, stream, b, um, (long)M_DIM, d2);
        hipLaunchKernelGGL(k_f_t, dim3(1), dim3(64), 0, stream, d1, d2, xtpx, p, Fp);
        hipLaunchKernelGGL(k_sp, g(NNZ_P), dim3(TPB), 0, stream, Pv, Pr, Pc, Fp, Ap, 1.0, (long)NNZ_P);
        hipLaunchKernelGGL(k_sp, g(NNZ_A), dim3(TPB), 0, stream, Av, Ac, Ar, Fp + N_DIM, Ap, -1.0, (long)NNZ_A);
        hipLaunchKernelGGL(k_ft_n, g(N_DIM), dim3(TPB), 0, stream, c3, Fp, Ap);
        hipLaunchKernelGGL(k_sp, g(NNZ_A), dim3(TPB), 0, stream, Av, Ar, Ac, Fp, tm, 1.0, (long)NNZ_A);
        hipLaunchKernelGGL(k_ft_m, g(M_DIM), dim3(TPB), 0, stream, mask_d, b, tm, Fp, Ap);
        hipLaunchKernelGGL(k_dot_fd, g(N_DIM), dim3(TPB), 0, stream, q, Fp, (long)N_DIM, e1);
        hipLaunchKernelGGL(k_dot_fd, g(M_DIM), dim3(TPB), 0, stream, b, Fp + N_DIM, (long)M_DIM, e2);
        hipLaunchKernelGGL(k_ft_t, dim3(1), dim3(64), 0, stream, e1, e2, xtpx, Fp, Ap);
        hipLaunchKernelGGL(k_dot_dd, g(NM1), dim3(TPB), 0, stream, p, Ap, (long)NM1, pq);
        hipLaunchKernelGGL(k_xr, g(NM1), dim3(TPB), 0, stream, p, Ap, gam + it, pq, xcg, r, gam + it + 1);
        hipLaunchKernelGGL(k_up, g(NM1), dim3(TPB), 0, stream, r, gam + it + 1, gam + it, p);
    }

    hipLaunchKernelGGL(k_final, g(NMSUM), dim3(TPB), 0, stream, xcg, mask_d, x, yv, sv, out);
}